// Round 1
// baseline (215.073 us; speedup 1.0000x reference)
//
#include <hip/hip_runtime.h>
#include <stdint.h>
#include <math.h>

// LabelCls: cascade label assignment.
// Layout: inputs (64, 3*65536) f32; cascade h occupies columns [h*65536,(h+1)*65536).
// One block per (h, batch_row): 192 blocks x 1024 threads.
//
// RNG: JAX threefry2x32, *partitionable* mode (default in modern JAX):
//   keys[h]   = TF((0,42), (0,h))           (fold-like split)
//   bits(i)   = x0 ^ x1 of TF(key_h, (0,i)) (i = linear index in (64,65536))
//   u         = bitcast((bits>>9)|0x3f800000) - 1.0f
//
// Selection: kth-largest values (k=16 pos / k=48 neg) are guaranteed > FILT0=0.98
// for this data (>=16 of ~13k+ uniforms above 0.98: >10 sigma). Candidates >0.98
// collected into LDS, exact rank-select (handles ties identically to lax.top_k).
// Fallback refinement loops + no-positive branch cover degenerate rows (unused here).

#define NROI 65536
#define ROWSTRIDE (3 * 65536)
#define CAP 2048
#define FILT0 0.98f
#define NTHREADS 1024
#define NITER 16   // 65536 / 4 / 1024

// ---------------- threefry2x32 (20 rounds) ----------------
#define TF_ROUNDS(x0, x1, R0, R1, R2, R3)                         \
  x0 += x1; x1 = (x1 << R0) | (x1 >> (32 - R0)); x1 ^= x0;        \
  x0 += x1; x1 = (x1 << R1) | (x1 >> (32 - R1)); x1 ^= x0;        \
  x0 += x1; x1 = (x1 << R2) | (x1 >> (32 - R2)); x1 ^= x0;        \
  x0 += x1; x1 = (x1 << R3) | (x1 >> (32 - R3)); x1 ^= x0;

#define TF_BODY(k0, k1, k2, x0, x1)                               \
  TF_ROUNDS(x0, x1, 13, 15, 26, 6)  x0 += k1; x1 += k2 + 1u;      \
  TF_ROUNDS(x0, x1, 17, 29, 16, 24) x0 += k2; x1 += k0 + 2u;      \
  TF_ROUNDS(x0, x1, 13, 15, 26, 6)  x0 += k0; x1 += k1 + 3u;      \
  TF_ROUNDS(x0, x1, 17, 29, 16, 24) x0 += k1; x1 += k2 + 4u;      \
  TF_ROUNDS(x0, x1, 13, 15, 26, 6)  x0 += k2; x1 += k0 + 5u;

__device__ __forceinline__ float tf_uniform(uint32_t k0, uint32_t k1, uint32_t idx) {
  uint32_t k2 = k0 ^ k1 ^ 0x1BD11BDAu;
  uint32_t x0 = 0u + k0;     // counts_hi = 0 (size < 2^32)
  uint32_t x1 = idx + k1;    // counts_lo = linear index
  TF_BODY(k0, k1, k2, x0, x1)
  uint32_t bits = x0 ^ x1;   // partitionable 32-bit output
  return __uint_as_float((bits >> 9) | 0x3f800000u) - 1.0f;
}

static void tf_pair_host(uint32_t k0, uint32_t k1, uint32_t c0, uint32_t c1,
                         uint32_t* o0, uint32_t* o1) {
  uint32_t k2 = k0 ^ k1 ^ 0x1BD11BDAu;
  uint32_t x0 = c0 + k0, x1 = c1 + k1;
  TF_BODY(k0, k1, k2, x0, x1)
  *o0 = x0; *o1 = x1;
}

// ---------------- kernel ----------------
__global__ __launch_bounds__(NTHREADS) void label_kernel(
    const float* __restrict__ ov, const float* __restrict__ iu,
    const float* __restrict__ nm, float* __restrict__ out,
    uint32_t K00, uint32_t K01, uint32_t K10, uint32_t K11,
    uint32_t K20, uint32_t K21) {
  const int bid = blockIdx.x;
  const int h = bid >> 6;
  const int b = bid & 63;
  const int tid = threadIdx.x;

  const float POS_T = (h == 0) ? 0.6f : ((h == 1) ? 0.7f : 0.8f);
  const float IOU_T = (h == 0) ? 0.2f : ((h == 1) ? 0.3f : 0.4f);
  const float NEG_T = 0.3f;
  const uint32_t k0 = (h == 0) ? K00 : ((h == 1) ? K10 : K20);
  const uint32_t k1 = (h == 0) ? K01 : ((h == 1) ? K11 : K21);

  const size_t rowoff = (size_t)b * ROWSTRIDE + (size_t)h * NROI;
  const float4* ov4 = (const float4*)(ov + rowoff);
  const float4* iu4 = (const float4*)(iu + rowoff);
  float4* out4 = (float4*)(out + rowoff);
  const uint32_t ibase = (uint32_t)b * (uint32_t)NROI;

  __shared__ float ival[CAP];
  __shared__ int   iidx[CAP];
  __shared__ float sval[CAP];
  __shared__ int   sidx[CAP];
  __shared__ uint32_t bitmap[NROI / 32];
  __shared__ int s_nci, s_ncs, s_poscnt;
  __shared__ uint32_t s_maxbits;
  __shared__ float s_kth16, s_top2, s_kth48;

  if (tid == 0) { s_nci = 0; s_ncs = 0; s_poscnt = 0; s_maxbits = 0u; }
  for (int w = tid; w < NROI / 32; w += NTHREADS) bitmap[w] = 0u;
  __syncthreads();

  // ---- Phase A: single stream over the row ----
  int poscnt_l = 0;
  uint32_t maxb_l = 0u;
#pragma unroll 1
  for (int it = 0; it < NITER; ++it) {
    int v4i = it * NTHREADS + tid;
    float4 o = ov4[v4i];
    float4 q = iu4[v4i];
    int j0 = v4i * 4;
    float ov_[4] = {o.x, o.y, o.z, o.w};
    float iu_[4] = {q.x, q.y, q.z, q.w};
#pragma unroll
    for (int c = 0; c < 4; ++c) {
      float ovv = ov_[c], iuv = iu_[c];
      int j = j0 + c;
      bool pos = ovv >= POS_T;
      poscnt_l += pos ? 1 : 0;
      uint32_t ib = __float_as_uint(iuv);  // iou >= 0: bit order == value order
      maxb_l = ib > maxb_l ? ib : maxb_l;
      if (pos && iuv > FILT0) {
        int p = atomicAdd(&s_nci, 1);
        if (p < CAP) { ival[p] = iuv; iidx[p] = j; }
      }
      if (ovv <= NEG_T) {
        float u = tf_uniform(k0, k1, ibase + (uint32_t)j);
        if (u > FILT0) {
          int p = atomicAdd(&s_ncs, 1);
          if (p < CAP) { sval[p] = u; sidx[p] = j; }
        }
      }
    }
  }
  atomicAdd(&s_poscnt, poscnt_l);
  atomicMax(&s_maxbits, maxb_l);
  __syncthreads();

  int nci = min(s_nci, CAP);
  int ncs = min(s_ncs, CAP);
  const int pos_cnt = s_poscnt;
  const float max_iou = __uint_as_float(s_maxbits);

  float kth16 = 0.f, top2 = 0.f;

  if (pos_cnt == 0) {
    // Degenerate: iou_masked nonzero only where iou == max. Repopulate list.
    if (tid == 0) s_nci = 0;
    __syncthreads();
#pragma unroll 1
    for (int it = 0; it < NITER; ++it) {
      int v4i = it * NTHREADS + tid;
      float4 q = iu4[v4i];
      int j0 = v4i * 4;
      float iu_[4] = {q.x, q.y, q.z, q.w};
#pragma unroll
      for (int c = 0; c < 4; ++c) {
        if (__float_as_uint(iu_[c]) == s_maxbits) {
          int p = atomicAdd(&s_nci, 1);
          if (p < CAP) { ival[p] = iu_[c]; iidx[p] = j0 + c; }
        }
      }
    }
    __syncthreads();
    int cmax = s_nci;
    nci = min(cmax, CAP);
    kth16 = (cmax >= 16) ? max_iou : 0.f;
    top2 = (cmax >= 2) ? max_iou : 0.f;
  } else {
    // Refinement (expected to never trigger: ~500 cands >> 16).
    float lo = FILT0;
    while (nci < 16 && nci < pos_cnt && lo > 0.f) {
      float hi = lo;
      lo = fmaxf(0.f, 1.f - 2.f * (1.f - lo));
      __syncthreads();
#pragma unroll 1
      for (int it = 0; it < NITER; ++it) {
        int v4i = it * NTHREADS + tid;
        float4 o = ov4[v4i];
        float4 q = iu4[v4i];
        int j0 = v4i * 4;
        float ov_[4] = {o.x, o.y, o.z, o.w};
        float iu_[4] = {q.x, q.y, q.z, q.w};
#pragma unroll
        for (int c = 0; c < 4; ++c) {
          if (ov_[c] >= POS_T && iu_[c] > lo && iu_[c] <= hi) {
            int p = atomicAdd(&s_nci, 1);
            if (p < CAP) { ival[p] = iu_[c]; iidx[p] = j0 + c; }
          }
        }
      }
      __syncthreads();
      nci = min(s_nci, CAP);
    }
    // Exact rank select: positions 1 (top2) and 15 (kth16), descending, ties like top_k.
    if (tid == 0) { s_kth16 = 0.f; s_top2 = 0.f; }
    __syncthreads();
    for (int c = tid; c < nci; c += NTHREADS) {
      float v = ival[c];
      int g = 0, e = 0;
      for (int x = 0; x < nci; ++x) {
        float w = ival[x];
        g += (w > v) ? 1 : 0;
        e += (w == v) ? 1 : 0;
      }
      if (g <= 15 && 15 < g + e) s_kth16 = v;  // all writers hold the same value
      if (g <= 1 && 1 < g + e) s_top2 = v;
    }
    __syncthreads();
    kth16 = s_kth16;
    top2 = s_top2;
  }
  const float t = (kth16 >= IOU_T) ? kth16 : IOU_T;

  // ---- negative (score) selection ----
  {
    float lo = FILT0;
    while (ncs < 48 && lo > 0.f) {  // expected to never trigger (~390 cands)
      float hi = lo;
      lo = fmaxf(0.f, 1.f - 2.f * (1.f - lo));
      __syncthreads();
#pragma unroll 1
      for (int it = 0; it < NITER; ++it) {
        int v4i = it * NTHREADS + tid;
        float4 o = ov4[v4i];
        int j0 = v4i * 4;
        float ov_[4] = {o.x, o.y, o.z, o.w};
#pragma unroll
        for (int c = 0; c < 4; ++c) {
          if (ov_[c] <= NEG_T) {
            float u = tf_uniform(k0, k1, ibase + (uint32_t)(j0 + c));
            if (u > lo && u <= hi) {
              int p = atomicAdd(&s_ncs, 1);
              if (p < CAP) { sval[p] = u; sidx[p] = j0 + c; }
            }
          }
        }
      }
      __syncthreads();
      ncs = min(s_ncs, CAP);
    }
  }
  if (tid == 0) s_kth48 = -INFINITY;
  __syncthreads();
  for (int c = tid; c < ncs; c += NTHREADS) {
    float v = sval[c];
    int g = 0, e = 0;
    for (int x = 0; x < ncs; ++x) {
      float w = sval[x];
      g += (w > v) ? 1 : 0;
      e += (w == v) ? 1 : 0;
    }
    if (g <= 47 && 47 < g + e) s_kth48 = v;
  }
  __syncthreads();
  const float kth48 = s_kth48;  // -inf if ncs<48 -> all eligible become neg
  for (int c = tid; c < ncs; c += NTHREADS) {
    if (sval[c] >= kth48) atomicOr(&bitmap[sidx[c] >> 5], 1u << (sidx[c] & 31));
  }
  __syncthreads();

  // ---- Phase C: stream base labels (-1 + neg), no input re-read ----
#pragma unroll 1
  for (int it = 0; it < NITER; ++it) {
    int v4i = it * NTHREADS + tid;
    int j0 = v4i * 4;
    uint32_t w = bitmap[j0 >> 5];  // 4-aligned: all 4 bits in one word
    uint32_t sh = (uint32_t)(j0 & 31);
    float4 r;
    r.x = -1.f + (float)((w >> (sh + 0)) & 1u);
    r.y = -1.f + (float)((w >> (sh + 1)) & 1u);
    r.z = -1.f + (float)((w >> (sh + 2)) & 1u);
    r.w = -1.f + (float)((w >> (sh + 3)) & 1u);
    out4[v4i] = r;
  }
  __syncthreads();  // drains vmcnt: base stores visible in L2 before RMW below

  // Sparse positive updates: +2 * neg_mask at pos indices (all pos are candidates).
  for (int c = tid; c < nci; c += NTHREADS) {
    float v = ival[c];
    bool pos = (v >= t) || (h == 0 && v > top2);
    if (pos) {
      size_t gi = rowoff + (size_t)iidx[c];
      float nmv = nm[gi];
      if (nmv != 0.f) atomicAdd(&out[gi], 2.f * nmv);
    }
  }
}

extern "C" void kernel_launch(void* const* d_in, const int* in_sizes, int n_in,
                              void* d_out, int out_size, void* d_ws, size_t ws_size,
                              hipStream_t stream) {
  const float* ov = (const float*)d_in[0];
  const float* iu = (const float*)d_in[1];
  const float* nm = (const float*)d_in[2];
  float* out = (float*)d_out;

  // keys[h] = threefry((0,42), (0,h))  -- fold-like split of jax.random.key(42)
  uint32_t ka[3], kb[3];
  for (uint32_t h = 0; h < 3; ++h) tf_pair_host(0u, 42u, 0u, h, &ka[h], &kb[h]);

  hipLaunchKernelGGL(label_kernel, dim3(192), dim3(NTHREADS), 0, stream,
                     ov, iu, nm, out, ka[0], kb[0], ka[1], kb[1], ka[2], kb[2]);
}

// Round 2
// 207.890 us; speedup vs baseline: 1.0346x; 1.0346x over previous
//
#include <hip/hip_runtime.h>
#include <stdint.h>
#include <math.h>

// LabelCls cascade label assignment — 3-phase version.
// Layout: inputs (64, 3*65536) f32; cascade h = columns [h*65536,(h+1)*65536).
// row id = h*64 + b, 192 rows total.
//
// Phase 0: memset row counters in d_ws (tiny).
// Phase 1: 3072 blocks (16 segs/row) x 256 thr. Stream ov+iu once, write -1 base
//   labels, compact eligible (ov<=0.3) indices to LDS queue (ballot-aggregated),
//   dense threefry over queue, push candidates (>0.98) to per-row global lists.
// Phase 2: 192 blocks x 1024 thr. Exact rank-select (ties == lax.top_k) on the
//   short lists, sparse fixups: pos -> -1+2*nm, neg -> 0. Slow path = full
//   round-1 recompute if any counter anomaly (never fires on this data).
// Fallback: if ws_size too small, launch the validated round-1 mono kernel.
//
// RNG: JAX threefry2x32 partitionable mode (verified round 1, absmax 0):
//   keys[h] = TF((0,42),(0,h)); bits(i)=x0^x1 of TF(key_h,(0, b*65536+col));
//   u = bitcast((bits>>9)|0x3f800000)-1.

#define NROI 65536
#define ROWSTRIDE (3 * 65536)
#define CAP 2048      // phase2 / mono LDS list cap
#define FILT0 0.98f
#define SEGS 16
#define SEGLEN 4096   // NROI / SEGS
#define P1_THREADS 256
#define P2_THREADS 1024
#define LCAP 512      // phase1 per-block candidate cap (expected ~82 max, 19 sigma)
#define NITER 16      // mono/slow: 65536/4/1024

// ---------------- threefry2x32 (20 rounds) ----------------
#define TF_ROUNDS(x0, x1, R0, R1, R2, R3)                         \
  x0 += x1; x1 = (x1 << R0) | (x1 >> (32 - R0)); x1 ^= x0;        \
  x0 += x1; x1 = (x1 << R1) | (x1 >> (32 - R1)); x1 ^= x0;        \
  x0 += x1; x1 = (x1 << R2) | (x1 >> (32 - R2)); x1 ^= x0;        \
  x0 += x1; x1 = (x1 << R3) | (x1 >> (32 - R3)); x1 ^= x0;

#define TF_BODY(k0, k1, k2, x0, x1)                               \
  TF_ROUNDS(x0, x1, 13, 15, 26, 6)  x0 += k1; x1 += k2 + 1u;      \
  TF_ROUNDS(x0, x1, 17, 29, 16, 24) x0 += k2; x1 += k0 + 2u;      \
  TF_ROUNDS(x0, x1, 13, 15, 26, 6)  x0 += k0; x1 += k1 + 3u;      \
  TF_ROUNDS(x0, x1, 17, 29, 16, 24) x0 += k1; x1 += k2 + 4u;      \
  TF_ROUNDS(x0, x1, 13, 15, 26, 6)  x0 += k2; x1 += k0 + 5u;

__device__ __forceinline__ float tf_uniform(uint32_t k0, uint32_t k1, uint32_t idx) {
  uint32_t k2 = k0 ^ k1 ^ 0x1BD11BDAu;
  uint32_t x0 = 0u + k0;
  uint32_t x1 = idx + k1;
  TF_BODY(k0, k1, k2, x0, x1)
  uint32_t bits = x0 ^ x1;
  return __uint_as_float((bits >> 9) | 0x3f800000u) - 1.0f;
}

static void tf_pair_host(uint32_t k0, uint32_t k1, uint32_t c0, uint32_t c1,
                         uint32_t* o0, uint32_t* o1) {
  uint32_t k2 = k0 ^ k1 ^ 0x1BD11BDAu;
  uint32_t x0 = c0 + k0, x1 = c1 + k1;
  TF_BODY(k0, k1, k2, x0, x1)
  *o0 = x0; *o1 = x1;
}

__device__ __forceinline__ void row_consts(int h, uint32_t K00, uint32_t K01,
                                           uint32_t K10, uint32_t K11,
                                           uint32_t K20, uint32_t K21,
                                           float* POS_T, float* IOU_T,
                                           uint32_t* k0, uint32_t* k1) {
  *POS_T = (h == 0) ? 0.6f : ((h == 1) ? 0.7f : 0.8f);
  *IOU_T = (h == 0) ? 0.2f : ((h == 1) ? 0.3f : 0.4f);
  *k0 = (h == 0) ? K00 : ((h == 1) ? K10 : K20);
  *k1 = (h == 0) ? K01 : ((h == 1) ? K11 : K21);
}

// ---------------- Phase 1 ----------------
__global__ __launch_bounds__(P1_THREADS) void phase1(
    const float* __restrict__ ov, const float* __restrict__ iu,
    float* __restrict__ out, uint32_t* __restrict__ ctr,
    float* __restrict__ posv, int* __restrict__ posi,
    float* __restrict__ negv, int* __restrict__ negi, int CAPG,
    uint32_t K00, uint32_t K01, uint32_t K10, uint32_t K11,
    uint32_t K20, uint32_t K21) {
  const int row = blockIdx.x >> 4;  // SEGS = 16
  const int seg = blockIdx.x & 15;
  const int h = row >> 6;
  const int b = row & 63;
  const int tid = threadIdx.x;
  float POS_T, IOU_T; uint32_t k0, k1;
  row_consts(h, K00, K01, K10, K11, K20, K21, &POS_T, &IOU_T, &k0, &k1);

  const size_t rowoff = (size_t)b * ROWSTRIDE + (size_t)h * NROI;
  const int segoff = seg * SEGLEN;
  const float4* o4 = (const float4*)(ov + rowoff + segoff);
  const float4* q4 = (const float4*)(iu + rowoff + segoff);
  float4* w4 = (float4*)(out + rowoff + segoff);
  const uint32_t ibase = (uint32_t)b * 65536u + (uint32_t)segoff;

  __shared__ int queue[SEGLEN];
  __shared__ float lpv[LCAP]; __shared__ int lpi[LCAP];
  __shared__ float lnv[LCAP]; __shared__ int lni[LCAP];
  __shared__ int s_qn, s_np, s_nn, s_pc, s_bp, s_bn;
  __shared__ uint32_t s_mx;

  if (tid == 0) { s_qn = 0; s_np = 0; s_nn = 0; s_pc = 0; s_mx = 0u; }
  __syncthreads();

  int pc = 0;
  uint32_t mx = 0u;
  const int lane = tid & 63;
  const float4 m1 = make_float4(-1.f, -1.f, -1.f, -1.f);
#pragma unroll
  for (int it = 0; it < 4; ++it) {
    int v = it * P1_THREADS + tid;
    float4 o = o4[v];
    float4 q = q4[v];
    w4[v] = m1;
    int j0 = v * 4;
    float oo[4] = {o.x, o.y, o.z, o.w}, qq[4] = {q.x, q.y, q.z, q.w};
#pragma unroll
    for (int c = 0; c < 4; ++c) {
      float ovv = oo[c], iuv = qq[c];
      int j = j0 + c;
      bool pos = ovv >= POS_T;
      pc += pos ? 1 : 0;
      uint32_t ib = __float_as_uint(iuv);
      mx = ib > mx ? ib : mx;
      // ballot-aggregated queue push (1 LDS atomic per wave, dense write)
      bool el = ovv <= 0.3f;
      unsigned long long msk = __ballot(el);
      if (msk) {
        int lead = __ffsll(msk) - 1;
        int base = 0;
        if (lane == lead) base = atomicAdd(&s_qn, __popcll(msk));
        base = __shfl(base, lead, 64);
        if (el) queue[base + __popcll(msk & ((1ull << lane) - 1ull))] = j;
      }
      if (pos && iuv > FILT0) {
        int p = atomicAdd(&s_np, 1);
        if (p < LCAP) { lpv[p] = iuv; lpi[p] = segoff + j; }
      }
    }
  }
  atomicAdd(&s_pc, pc);
  atomicMax(&s_mx, mx);
  __syncthreads();

  const int qn = s_qn;
  for (int qi = tid; qi < qn; qi += P1_THREADS) {
    int j = queue[qi];
    float u = tf_uniform(k0, k1, ibase + (uint32_t)j);
    if (u > FILT0) {
      int p = atomicAdd(&s_nn, 1);
      if (p < LCAP) { lnv[p] = u; lni[p] = segoff + j; }
    }
  }
  __syncthreads();

  uint32_t* C = ctr + row * 8;
  if (tid == 0) {
    int np = s_np, nn = s_nn;
    uint32_t fl = 0u;
    if (np > LCAP) { fl |= 1u; np = LCAP; }
    if (nn > LCAP) { fl |= 2u; nn = LCAP; }
    s_bp = (int)atomicAdd(&C[0], (uint32_t)np);
    s_bn = (int)atomicAdd(&C[1], (uint32_t)nn);
    atomicAdd(&C[2], (uint32_t)s_pc);
    atomicMax(&C[3], s_mx);
    if (fl) atomicOr(&C[4], fl);
    s_np = np; s_nn = nn;
  }
  __syncthreads();
  const int np = s_np, nn = s_nn, bp = s_bp, bn = s_bn;
  float* pv = posv + (size_t)row * CAPG;
  int*   pi = posi + (size_t)row * CAPG;
  float* nv = negv + (size_t)row * CAPG;
  int*   ni = negi + (size_t)row * CAPG;
  for (int i = tid; i < np; i += P1_THREADS) {
    int g = bp + i;
    if (g < CAPG) { pv[g] = lpv[i]; pi[g] = lpi[i]; }
  }
  for (int i = tid; i < nn; i += P1_THREADS) {
    int g = bn + i;
    if (g < CAPG) { nv[g] = lnv[i]; ni[g] = lni[i]; }
  }
}

// ---------------- Phase 2 ----------------
__global__ __launch_bounds__(P2_THREADS) void phase2(
    const float* __restrict__ ov, const float* __restrict__ iu,
    const float* __restrict__ nm, float* __restrict__ out,
    const uint32_t* __restrict__ ctr,
    const float* __restrict__ posv, const int* __restrict__ posi,
    const float* __restrict__ negv, const int* __restrict__ negi, int CAPG,
    uint32_t K00, uint32_t K01, uint32_t K10, uint32_t K11,
    uint32_t K20, uint32_t K21) {
  const int row = blockIdx.x;
  const int h = row >> 6;
  const int b = row & 63;
  const int tid = threadIdx.x;
  float POS_T, IOU_T; uint32_t k0, k1;
  row_consts(h, K00, K01, K10, K11, K20, K21, &POS_T, &IOU_T, &k0, &k1);
  const float NEG_T = 0.3f;
  const size_t rowoff = (size_t)b * ROWSTRIDE + (size_t)h * NROI;
  const uint32_t ibase = (uint32_t)b * 65536u;

  __shared__ float ival[CAP];
  __shared__ int   iidx[CAP];
  __shared__ float sval[CAP];
  __shared__ int   sidx[CAP];
  __shared__ uint32_t bitmap[NROI / 32];
  __shared__ int s_nci, s_ncs, s_poscnt;
  __shared__ uint32_t s_maxbits;
  __shared__ float s_kth16, s_top2, s_kth48;

  const uint32_t* C = ctr + row * 8;
  const int cp = (int)C[0];
  const int cn = (int)C[1];
  const uint32_t fl = C[4];
  const bool fast = (fl == 0u) && cp >= 16 && cp <= CAPG && cn >= 48 && cn <= CAPG;

  if (fast) {
    for (int i = tid; i < cp; i += P2_THREADS) {
      ival[i] = posv[(size_t)row * CAPG + i];
      iidx[i] = posi[(size_t)row * CAPG + i];
    }
    for (int i = tid; i < cn; i += P2_THREADS) {
      sval[i] = negv[(size_t)row * CAPG + i];
      sidx[i] = negi[(size_t)row * CAPG + i];
    }
    if (tid == 0) { s_kth16 = 0.f; s_top2 = 0.f; s_kth48 = -INFINITY; }
    __syncthreads();
    for (int c = tid; c < cp; c += P2_THREADS) {
      float v = ival[c];
      int g = 0, e = 0;
      for (int x = 0; x < cp; ++x) {
        float w = ival[x];
        g += (w > v) ? 1 : 0;
        e += (w == v) ? 1 : 0;
      }
      if (g <= 15 && 15 < g + e) s_kth16 = v;
      if (g <= 1 && 1 < g + e) s_top2 = v;
    }
    for (int c = tid; c < cn; c += P2_THREADS) {
      float v = sval[c];
      int g = 0, e = 0;
      for (int x = 0; x < cn; ++x) {
        float w = sval[x];
        g += (w > v) ? 1 : 0;
        e += (w == v) ? 1 : 0;
      }
      if (g <= 47 && 47 < g + e) s_kth48 = v;
    }
    __syncthreads();
    // cp>=16 guarantees kth16 > FILT0 > IOU_T; formula kept for clarity
    const float t = (s_kth16 >= IOU_T) ? s_kth16 : IOU_T;
    const float top2 = s_top2;
    const float kth48 = s_kth48;
    for (int c = tid; c < cp; c += P2_THREADS) {
      float v = ival[c];
      bool pos = (v >= t) || (h == 0 && v > top2);
      if (pos) {
        size_t gi = rowoff + (size_t)iidx[c];
        out[gi] = -1.f + 2.f * nm[gi];  // neg=0 here (ov>=POS_T > NEG_T)
      }
    }
    for (int c = tid; c < cn; c += P2_THREADS) {
      if (sval[c] >= kth48) out[rowoff + (size_t)sidx[c]] = 0.f;  // -1 + 1
    }
    return;
  }

  // ---------- slow path: full row recompute (round-1 logic, validated) ----------
  const float4* ov4 = (const float4*)(ov + rowoff);
  const float4* iu4 = (const float4*)(iu + rowoff);
  float4* out4 = (float4*)(out + rowoff);

  if (tid == 0) { s_nci = 0; s_ncs = 0; s_poscnt = 0; s_maxbits = 0u; }
  for (int w = tid; w < NROI / 32; w += P2_THREADS) bitmap[w] = 0u;
  __syncthreads();

  int poscnt_l = 0;
  uint32_t maxb_l = 0u;
#pragma unroll 1
  for (int it = 0; it < NITER; ++it) {
    int v4i = it * P2_THREADS + tid;
    float4 o = ov4[v4i];
    float4 q = iu4[v4i];
    int j0 = v4i * 4;
    float ov_[4] = {o.x, o.y, o.z, o.w};
    float iu_[4] = {q.x, q.y, q.z, q.w};
#pragma unroll
    for (int c = 0; c < 4; ++c) {
      float ovv = ov_[c], iuv = iu_[c];
      int j = j0 + c;
      bool pos = ovv >= POS_T;
      poscnt_l += pos ? 1 : 0;
      uint32_t ib = __float_as_uint(iuv);
      maxb_l = ib > maxb_l ? ib : maxb_l;
      if (pos && iuv > FILT0) {
        int p = atomicAdd(&s_nci, 1);
        if (p < CAP) { ival[p] = iuv; iidx[p] = j; }
      }
      if (ovv <= NEG_T) {
        float u = tf_uniform(k0, k1, ibase + (uint32_t)j);
        if (u > FILT0) {
          int p = atomicAdd(&s_ncs, 1);
          if (p < CAP) { sval[p] = u; sidx[p] = j; }
        }
      }
    }
  }
  atomicAdd(&s_poscnt, poscnt_l);
  atomicMax(&s_maxbits, maxb_l);
  __syncthreads();

  int nci = min(s_nci, CAP);
  int ncs = min(s_ncs, CAP);
  const int pos_cnt = s_poscnt;
  const float max_iou = __uint_as_float(s_maxbits);

  float kth16 = 0.f, top2 = 0.f;

  if (pos_cnt == 0) {
    if (tid == 0) s_nci = 0;
    __syncthreads();
#pragma unroll 1
    for (int it = 0; it < NITER; ++it) {
      int v4i = it * P2_THREADS + tid;
      float4 q = iu4[v4i];
      int j0 = v4i * 4;
      float iu_[4] = {q.x, q.y, q.z, q.w};
#pragma unroll
      for (int c = 0; c < 4; ++c) {
        if (__float_as_uint(iu_[c]) == s_maxbits) {
          int p = atomicAdd(&s_nci, 1);
          if (p < CAP) { ival[p] = iu_[c]; iidx[p] = j0 + c; }
        }
      }
    }
    __syncthreads();
    int cmax = s_nci;
    nci = min(cmax, CAP);
    kth16 = (cmax >= 16) ? max_iou : 0.f;
    top2 = (cmax >= 2) ? max_iou : 0.f;
  } else {
    float lo = FILT0;
    while (nci < 16 && nci < pos_cnt && lo > 0.f) {
      float hi = lo;
      lo = fmaxf(0.f, 1.f - 2.f * (1.f - lo));
      __syncthreads();
#pragma unroll 1
      for (int it = 0; it < NITER; ++it) {
        int v4i = it * P2_THREADS + tid;
        float4 o = ov4[v4i];
        float4 q = iu4[v4i];
        int j0 = v4i * 4;
        float ov_[4] = {o.x, o.y, o.z, o.w};
        float iu_[4] = {q.x, q.y, q.z, q.w};
#pragma unroll
        for (int c = 0; c < 4; ++c) {
          if (ov_[c] >= POS_T && iu_[c] > lo && iu_[c] <= hi) {
            int p = atomicAdd(&s_nci, 1);
            if (p < CAP) { ival[p] = iu_[c]; iidx[p] = j0 + c; }
          }
        }
      }
      __syncthreads();
      nci = min(s_nci, CAP);
    }
    if (tid == 0) { s_kth16 = 0.f; s_top2 = 0.f; }
    __syncthreads();
    for (int c = tid; c < nci; c += P2_THREADS) {
      float v = ival[c];
      int g = 0, e = 0;
      for (int x = 0; x < nci; ++x) {
        float w = ival[x];
        g += (w > v) ? 1 : 0;
        e += (w == v) ? 1 : 0;
      }
      if (g <= 15 && 15 < g + e) s_kth16 = v;
      if (g <= 1 && 1 < g + e) s_top2 = v;
    }
    __syncthreads();
    kth16 = s_kth16;
    top2 = s_top2;
  }
  const float t = (kth16 >= IOU_T) ? kth16 : IOU_T;

  {
    float lo = FILT0;
    while (ncs < 48 && lo > 0.f) {
      float hi = lo;
      lo = fmaxf(0.f, 1.f - 2.f * (1.f - lo));
      __syncthreads();
#pragma unroll 1
      for (int it = 0; it < NITER; ++it) {
        int v4i = it * P2_THREADS + tid;
        float4 o = ov4[v4i];
        int j0 = v4i * 4;
        float ov_[4] = {o.x, o.y, o.z, o.w};
#pragma unroll
        for (int c = 0; c < 4; ++c) {
          if (ov_[c] <= NEG_T) {
            float u = tf_uniform(k0, k1, ibase + (uint32_t)(j0 + c));
            if (u > lo && u <= hi) {
              int p = atomicAdd(&s_ncs, 1);
              if (p < CAP) { sval[p] = u; sidx[p] = j0 + c; }
            }
          }
        }
      }
      __syncthreads();
      ncs = min(s_ncs, CAP);
    }
  }
  if (tid == 0) s_kth48 = -INFINITY;
  __syncthreads();
  for (int c = tid; c < ncs; c += P2_THREADS) {
    float v = sval[c];
    int g = 0, e = 0;
    for (int x = 0; x < ncs; ++x) {
      float w = sval[x];
      g += (w > v) ? 1 : 0;
      e += (w == v) ? 1 : 0;
    }
    if (g <= 47 && 47 < g + e) s_kth48 = v;
  }
  __syncthreads();
  const float kth48 = s_kth48;
  for (int c = tid; c < ncs; c += P2_THREADS) {
    if (sval[c] >= kth48) atomicOr(&bitmap[sidx[c] >> 5], 1u << (sidx[c] & 31));
  }
  __syncthreads();

#pragma unroll 1
  for (int it = 0; it < NITER; ++it) {
    int v4i = it * P2_THREADS + tid;
    int j0 = v4i * 4;
    uint32_t w = bitmap[j0 >> 5];
    uint32_t sh = (uint32_t)(j0 & 31);
    float4 r;
    r.x = -1.f + (float)((w >> (sh + 0)) & 1u);
    r.y = -1.f + (float)((w >> (sh + 1)) & 1u);
    r.z = -1.f + (float)((w >> (sh + 2)) & 1u);
    r.w = -1.f + (float)((w >> (sh + 3)) & 1u);
    out4[v4i] = r;
  }
  __syncthreads();

  for (int c = tid; c < nci; c += P2_THREADS) {
    float v = ival[c];
    bool pos = (v >= t) || (h == 0 && v > top2);
    if (pos) {
      size_t gi = rowoff + (size_t)iidx[c];
      float nmv = nm[gi];
      if (nmv != 0.f) atomicAdd(&out[gi], 2.f * nmv);
    }
  }
}

// ---------------- mono fallback (round-1 kernel, validated) ----------------
__global__ __launch_bounds__(P2_THREADS) void label_kernel_mono(
    const float* __restrict__ ov, const float* __restrict__ iu,
    const float* __restrict__ nm, float* __restrict__ out,
    uint32_t K00, uint32_t K01, uint32_t K10, uint32_t K11,
    uint32_t K20, uint32_t K21) {
  const int bid = blockIdx.x;
  const int h = bid >> 6;
  const int b = bid & 63;
  const int tid = threadIdx.x;
  float POS_T, IOU_T; uint32_t k0, k1;
  row_consts(h, K00, K01, K10, K11, K20, K21, &POS_T, &IOU_T, &k0, &k1);
  const float NEG_T = 0.3f;
  const size_t rowoff = (size_t)b * ROWSTRIDE + (size_t)h * NROI;
  const float4* ov4 = (const float4*)(ov + rowoff);
  const float4* iu4 = (const float4*)(iu + rowoff);
  float4* out4 = (float4*)(out + rowoff);
  const uint32_t ibase = (uint32_t)b * (uint32_t)NROI;

  __shared__ float ival[CAP];
  __shared__ int   iidx[CAP];
  __shared__ float sval[CAP];
  __shared__ int   sidx[CAP];
  __shared__ uint32_t bitmap[NROI / 32];
  __shared__ int s_nci, s_ncs, s_poscnt;
  __shared__ uint32_t s_maxbits;
  __shared__ float s_kth16, s_top2, s_kth48;

  if (tid == 0) { s_nci = 0; s_ncs = 0; s_poscnt = 0; s_maxbits = 0u; }
  for (int w = tid; w < NROI / 32; w += P2_THREADS) bitmap[w] = 0u;
  __syncthreads();

  int poscnt_l = 0;
  uint32_t maxb_l = 0u;
#pragma unroll 1
  for (int it = 0; it < NITER; ++it) {
    int v4i = it * P2_THREADS + tid;
    float4 o = ov4[v4i];
    float4 q = iu4[v4i];
    int j0 = v4i * 4;
    float ov_[4] = {o.x, o.y, o.z, o.w};
    float iu_[4] = {q.x, q.y, q.z, q.w};
#pragma unroll
    for (int c = 0; c < 4; ++c) {
      float ovv = ov_[c], iuv = iu_[c];
      int j = j0 + c;
      bool pos = ovv >= POS_T;
      poscnt_l += pos ? 1 : 0;
      uint32_t ib = __float_as_uint(iuv);
      maxb_l = ib > maxb_l ? ib : maxb_l;
      if (pos && iuv > FILT0) {
        int p = atomicAdd(&s_nci, 1);
        if (p < CAP) { ival[p] = iuv; iidx[p] = j; }
      }
      if (ovv <= NEG_T) {
        float u = tf_uniform(k0, k1, ibase + (uint32_t)j);
        if (u > FILT0) {
          int p = atomicAdd(&s_ncs, 1);
          if (p < CAP) { sval[p] = u; sidx[p] = j; }
        }
      }
    }
  }
  atomicAdd(&s_poscnt, poscnt_l);
  atomicMax(&s_maxbits, maxb_l);
  __syncthreads();

  int nci = min(s_nci, CAP);
  int ncs = min(s_ncs, CAP);
  const int pos_cnt = s_poscnt;
  const float max_iou = __uint_as_float(s_maxbits);

  float kth16 = 0.f, top2 = 0.f;

  if (pos_cnt == 0) {
    if (tid == 0) s_nci = 0;
    __syncthreads();
#pragma unroll 1
    for (int it = 0; it < NITER; ++it) {
      int v4i = it * P2_THREADS + tid;
      float4 q = iu4[v4i];
      int j0 = v4i * 4;
      float iu_[4] = {q.x, q.y, q.z, q.w};
#pragma unroll
      for (int c = 0; c < 4; ++c) {
        if (__float_as_uint(iu_[c]) == s_maxbits) {
          int p = atomicAdd(&s_nci, 1);
          if (p < CAP) { ival[p] = iu_[c]; iidx[p] = j0 + c; }
        }
      }
    }
    __syncthreads();
    int cmax = s_nci;
    nci = min(cmax, CAP);
    kth16 = (cmax >= 16) ? max_iou : 0.f;
    top2 = (cmax >= 2) ? max_iou : 0.f;
  } else {
    float lo = FILT0;
    while (nci < 16 && nci < pos_cnt && lo > 0.f) {
      float hi = lo;
      lo = fmaxf(0.f, 1.f - 2.f * (1.f - lo));
      __syncthreads();
#pragma unroll 1
      for (int it = 0; it < NITER; ++it) {
        int v4i = it * P2_THREADS + tid;
        float4 o = ov4[v4i];
        float4 q = iu4[v4i];
        int j0 = v4i * 4;
        float ov_[4] = {o.x, o.y, o.z, o.w};
        float iu_[4] = {q.x, q.y, q.z, q.w};
#pragma unroll
        for (int c = 0; c < 4; ++c) {
          if (ov_[c] >= POS_T && iu_[c] > lo && iu_[c] <= hi) {
            int p = atomicAdd(&s_nci, 1);
            if (p < CAP) { ival[p] = iu_[c]; iidx[p] = j0 + c; }
          }
        }
      }
      __syncthreads();
      nci = min(s_nci, CAP);
    }
    if (tid == 0) { s_kth16 = 0.f; s_top2 = 0.f; }
    __syncthreads();
    for (int c = tid; c < nci; c += P2_THREADS) {
      float v = ival[c];
      int g = 0, e = 0;
      for (int x = 0; x < nci; ++x) {
        float w = ival[x];
        g += (w > v) ? 1 : 0;
        e += (w == v) ? 1 : 0;
      }
      if (g <= 15 && 15 < g + e) s_kth16 = v;
      if (g <= 1 && 1 < g + e) s_top2 = v;
    }
    __syncthreads();
    kth16 = s_kth16;
    top2 = s_top2;
  }
  const float t = (kth16 >= IOU_T) ? kth16 : IOU_T;

  {
    float lo = FILT0;
    while (ncs < 48 && lo > 0.f) {
      float hi = lo;
      lo = fmaxf(0.f, 1.f - 2.f * (1.f - lo));
      __syncthreads();
#pragma unroll 1
      for (int it = 0; it < NITER; ++it) {
        int v4i = it * P2_THREADS + tid;
        float4 o = ov4[v4i];
        int j0 = v4i * 4;
        float ov_[4] = {o.x, o.y, o.z, o.w};
#pragma unroll
        for (int c = 0; c < 4; ++c) {
          if (ov_[c] <= NEG_T) {
            float u = tf_uniform(k0, k1, ibase + (uint32_t)(j0 + c));
            if (u > lo && u <= hi) {
              int p = atomicAdd(&s_ncs, 1);
              if (p < CAP) { sval[p] = u; sidx[p] = j0 + c; }
            }
          }
        }
      }
      __syncthreads();
      ncs = min(s_ncs, CAP);
    }
  }
  if (tid == 0) s_kth48 = -INFINITY;
  __syncthreads();
  for (int c = tid; c < ncs; c += P2_THREADS) {
    float v = sval[c];
    int g = 0, e = 0;
    for (int x = 0; x < ncs; ++x) {
      float w = sval[x];
      g += (w > v) ? 1 : 0;
      e += (w == v) ? 1 : 0;
    }
    if (g <= 47 && 47 < g + e) s_kth48 = v;
  }
  __syncthreads();
  const float kth48 = s_kth48;
  for (int c = tid; c < ncs; c += P2_THREADS) {
    if (sval[c] >= kth48) atomicOr(&bitmap[sidx[c] >> 5], 1u << (sidx[c] & 31));
  }
  __syncthreads();

#pragma unroll 1
  for (int it = 0; it < NITER; ++it) {
    int v4i = it * P2_THREADS + tid;
    int j0 = v4i * 4;
    uint32_t w = bitmap[j0 >> 5];
    uint32_t sh = (uint32_t)(j0 & 31);
    float4 r;
    r.x = -1.f + (float)((w >> (sh + 0)) & 1u);
    r.y = -1.f + (float)((w >> (sh + 1)) & 1u);
    r.z = -1.f + (float)((w >> (sh + 2)) & 1u);
    r.w = -1.f + (float)((w >> (sh + 3)) & 1u);
    out4[v4i] = r;
  }
  __syncthreads();

  for (int c = tid; c < nci; c += P2_THREADS) {
    float v = ival[c];
    bool pos = (v >= t) || (h == 0 && v > top2);
    if (pos) {
      size_t gi = rowoff + (size_t)iidx[c];
      float nmv = nm[gi];
      if (nmv != 0.f) atomicAdd(&out[gi], 2.f * nmv);
    }
  }
}

extern "C" void kernel_launch(void* const* d_in, const int* in_sizes, int n_in,
                              void* d_out, int out_size, void* d_ws, size_t ws_size,
                              hipStream_t stream) {
  const float* ov = (const float*)d_in[0];
  const float* iu = (const float*)d_in[1];
  const float* nm = (const float*)d_in[2];
  float* out = (float*)d_out;

  uint32_t ka[3], kb[3];
  for (uint32_t h = 0; h < 3; ++h) tf_pair_host(0u, 42u, 0u, h, &ka[h], &kb[h]);

  const size_t ctr_bytes = 192 * 8 * sizeof(uint32_t);  // 6144
  int CAPG = 1536;
  if (ws_size < ctr_bytes + (size_t)192 * CAPG * 16) {
    CAPG = (ws_size > ctr_bytes) ? (int)((ws_size - ctr_bytes) / (192 * 16)) : 0;
  }

  if (CAPG >= 256) {
    uint32_t* ctr = (uint32_t*)d_ws;
    float* posv = (float*)((char*)d_ws + ctr_bytes);
    int*   posi = (int*)(posv + (size_t)192 * CAPG);
    float* negv = (float*)(posi + (size_t)192 * CAPG);
    int*   negi = (int*)(negv + (size_t)192 * CAPG);
    hipMemsetAsync(d_ws, 0, ctr_bytes, stream);
    hipLaunchKernelGGL(phase1, dim3(192 * SEGS), dim3(P1_THREADS), 0, stream,
                       ov, iu, out, ctr, posv, posi, negv, negi, CAPG,
                       ka[0], kb[0], ka[1], kb[1], ka[2], kb[2]);
    hipLaunchKernelGGL(phase2, dim3(192), dim3(P2_THREADS), 0, stream,
                       ov, iu, nm, out, ctr, posv, posi, negv, negi, CAPG,
                       ka[0], kb[0], ka[1], kb[1], ka[2], kb[2]);
  } else {
    hipLaunchKernelGGL(label_kernel_mono, dim3(192), dim3(P2_THREADS), 0, stream,
                       ov, iu, nm, out, ka[0], kb[0], ka[1], kb[1], ka[2], kb[2]);
  }
}